// Round 1
// baseline (82.287 us; speedup 1.0000x reference)
//
#include <hip/hip_runtime.h>

// KAN layer: out[b,o] = sum_i [ sum_g w[o,i,g]*exp(-|tanh(x[b,i])-grid[g]|*s[o,i])
//                               + ba[o,i]*tanh(x[b,i]) ]
// Factorization: exp(-s|xn-g|) = exp(-s*xn)*[w*e^{s*g}]   (g <= xn)
//                              = exp(+s*xn)*[w*e^{-s*g}]  (g >  xn)
// Prefix/suffix tables per (o,i) over the 5 split points k (xn in (-1,1) =>
// k in [2,6]); per (b,o,i): 2 exp2 + 3 fma + one 8B table read (L2-hot).
//
// R7: occupancy fix (512 blocks x 512 threads, 4 waves/SIMD) -> 80.5 us.
// R8 (this): scalarize wave-uniform address work. The T-row offset and the
// wave's i0 are wave-uniform; readfirstlane them so the T load becomes
// SGPR-base + hoisted VGPR offset (o*8), and pack the per-i (xn,row) pairs
// for both b's into one float4 -> one ds_read_b128 instead of two
// ds_read_b64. Cuts ~5 VALU issue slots per i-iteration in the hot loop.
// Structural harness floor measured R5: ~72.6 us.

#define B_   256
#define OUT_ 256
#define IN_  256
#define G_   8
#define NK   5           // k' = k-2
#define BT   2           // b's per main block (register-blocked)
#define OT   64          // o-tile = one wave width
#define NW   8           // waves per main block
#define IW   (IN_/NW)    // 32 i's per wave

// ---------------------------------------------------------------------------
// Kernel 1 (prep), grid 256 x 256:
//  part A: idx=(b,i) i-fast  -> xn=tanh(x), precomputed T-row. Coalesced R/W.
//  part B: i=blockIdx, o=tid -> per-(o,i) tables; stores coalesced 512B/wave
//          (T layout [k'][i][o], o fast, matching main's reads).
// ---------------------------------------------------------------------------
__global__ __launch_bounds__(256) void kan_prep(
        const float* __restrict__ x,
        const float* __restrict__ w,
        const float* __restrict__ sc,
        const float* __restrict__ ba,
        const float* __restrict__ grid,
        float2* __restrict__ xnk,
        float2* __restrict__ sbt,
        float2* __restrict__ T)
{
    float g[G_];
#pragma unroll
    for (int j = 0; j < G_; ++j) g[j] = grid[j];   // uniform broadcast loads

    // ---- part A: one (b,i) per thread, i fast -> coalesced
    {
        const int idx = blockIdx.x * 256 + threadIdx.x;
        const float xn = tanhf(x[idx]);
        int k = 0;
#pragma unroll
        for (int j = 0; j < G_; ++j) k += (g[j] <= xn) ? 1 : 0;
        k = min(max(k, 2), 6) - 2;                 // 0..4
        const int row = k * IN_ + (idx & (IN_ - 1));
        xnk[idx] = make_float2(xn, __int_as_float(row));
    }

    // ---- part B: one i per block, o = tid -> all stores coalesced
    {
        const int i = blockIdx.x;
        const int o = threadIdx.x;
        const int base = o * IN_ + i;              // strided reads (L2-hot)
        const float s  = sc[base];
        const float bv = ba[base];

        float Ep[G_], Em[G_];
#pragma unroll
        for (int j = 0; j < G_; ++j) {
            const float wv = w[base * G_ + j];
            const float t  = s * g[j];
            Ep[j] = wv * __expf(t);
            Em[j] = wv * __expf(-t);
        }
#pragma unroll
        for (int kk = 0; kk < NK; ++kk) {
            const int k = kk + 2;
            float A = 0.f, Bv = 0.f;
#pragma unroll
            for (int j = 0; j < G_; ++j) {
                if (j < k) A += Ep[j]; else Bv += Em[j];   // static split
            }
            T[(kk * IN_ + i) * OUT_ + o] = make_float2(A, Bv);  // 512B/wave
        }
        sbt[i * OUT_ + o] = make_float2(s * 1.44269504088896340736f, bv);
    }
}

// ---------------------------------------------------------------------------
// Kernel 2 (main): grid = (B/BT)=128 b-groups x 4 o-tiles = 512 blocks,
// 512 threads = 8 waves (2 blocks/CU -> 4 waves/SIMD). Wave ig owns 32 i's,
// 64 o-lanes, BT=2 b's. Full i-reduction via LDS tree -> direct d_out store.
// Per (b,o,i): 1 LDS broadcast (shared b128) + 1 L2 8B read (SGPR base) +
// 2 exp2 + 3 fma.
// ---------------------------------------------------------------------------
__global__ __launch_bounds__(512, 4) void kan_main(
        const float2* __restrict__ xnk,
        const float2* __restrict__ sbt,
        const float2* __restrict__ T,
        float* __restrict__ out)
{
    const int lane = threadIdx.x & 63;
    const int igrp = threadIdx.x >> 6;          // 0..7
    const int ot   = blockIdx.x & 3;            // 4 o-tiles
    const int bg   = blockIdx.x >> 2;           // 128 b-groups
    const int o    = ot * OT + lane;
    const int b0   = bg * BT;

    __shared__ float4 sxk4[IN_];                // 4 KB: (xn0,row0,xn1,row1) per i
    __shared__ float  sacc[NW][BT][OT];         // 4 KB: per-wave partials

    if (threadIdx.x < IN_) {
        const int t = threadIdx.x;
        const float2 v0 = xnk[b0 * IN_ + t];            // coalesced 8B
        const float2 v1 = xnk[(b0 + 1) * IN_ + t];      // coalesced 8B
        // pre-shift row*OUT_ so the hot loop does scalar base math only
        sxk4[t] = make_float4(
            v0.x, __int_as_float(__float_as_int(v0.y) << 8),
            v1.x, __int_as_float(__float_as_int(v1.y) << 8));
    }
    __syncthreads();

    float acc0 = 0.f, acc1 = 0.f;

    // wave-uniform scalars: i0 in SGPR; per-lane byte offset o*8 hoisted
    const int i0 = __builtin_amdgcn_readfirstlane(igrp * IW);
    const int o8 = o * (int)sizeof(float2);

#pragma unroll 4
    for (int ii = 0; ii < IW; ++ii) {
        const int i = i0 + ii;                    // scalar
        const float2 sb = sbt[i * OUT_ + o];      // 512B/wave, L2-hot
        const float4 xk = sxk4[i];                // one ds_read_b128, broadcast
        // rows are wave-uniform -> fold into SGPR base of the T load
        const int r0 = __builtin_amdgcn_readfirstlane(__float_as_int(xk.y));
        const int r1 = __builtin_amdgcn_readfirstlane(__float_as_int(xk.w));
        const float2 rec0 = *reinterpret_cast<const float2*>(
            reinterpret_cast<const char*>(T + r0) + o8);
        const float2 rec1 = *reinterpret_cast<const float2*>(
            reinterpret_cast<const char*>(T + r1) + o8);

        // bb = 0
        const float t0 = sb.x * xk.x;             // s*log2e*xn
        float a0 = fmaf(sb.y, xk.x, acc0);        // + ba*xn
        a0   = fmaf(exp2f(-t0), rec0.x, a0);      // + e^{-s*xn} * A[k]
        acc0 = fmaf(exp2f(t0),  rec0.y, a0);      // + e^{+s*xn} * B[k]
        // bb = 1
        const float t1 = sb.x * xk.z;
        float a1 = fmaf(sb.y, xk.z, acc1);
        a1   = fmaf(exp2f(-t1), rec1.x, a1);
        acc1 = fmaf(exp2f(t1),  rec1.y, a1);
    }

    sacc[igrp][0][lane] = acc0;
    sacc[igrp][1][lane] = acc1;
    __syncthreads();

    if (threadIdx.x < BT * OT) {
        const int bb = threadIdx.x >> 6;
        const int l  = threadIdx.x & 63;
        float s = 0.f;
#pragma unroll
        for (int wv = 0; wv < NW; ++wv) s += sacc[wv][bb][l];
        out[(b0 + bb) * OUT_ + ot * OT + l] = s;  // coalesced, full overwrite
    }
}

// ---------------------------------------------------------------------------
extern "C" void kernel_launch(void* const* d_in, const int* in_sizes, int n_in,
                              void* d_out, int out_size, void* d_ws, size_t ws_size,
                              hipStream_t stream)
{
    const float* x    = (const float*)d_in[0];
    const float* w    = (const float*)d_in[1];   // (OUT, IN, G)
    const float* sc   = (const float*)d_in[2];   // (OUT, IN)
    const float* ba   = (const float*)d_in[3];   // (OUT, IN)
    const float* grid = (const float*)d_in[4];   // (G)
    float* out = (float*)d_out;

    // ws: xnk 512KB | sbt 512KB | T 2.5MB   (3.5 MB total)
    char* ws = (char*)d_ws;
    float2* xnk = (float2*)(ws);
    float2* sbt = (float2*)(ws + 512 * 1024);
    float2* T   = (float2*)(ws + 1024 * 1024);

    kan_prep<<<IN_, 256, 0, stream>>>(x, w, sc, ba, grid, xnk, sbt, T);
    kan_main<<<(B_ / BT) * (OUT_ / OT), 512, 0, stream>>>(xnk, sbt, T, out);
}